// Round 18
// baseline (267.001 us; speedup 1.0000x reference)
//
#include <hip/hip_runtime.h>
#include <hip/hip_fp16.h>
#include <stdint.h>

typedef _Float16 f16x8 __attribute__((ext_vector_type(8)));
typedef _Float16 f16x4 __attribute__((ext_vector_type(4)));
typedef float    f32x4 __attribute__((ext_vector_type(4)));

#define MFMA16(a, b, c) __builtin_amdgcn_mfma_f32_16x16x32_f16(a, b, c, 0, 0, 0)

static constexpr int BN   = 8;
static constexpr int CIN  = 512;
static constexpr int NHW  = 4096;
static constexpr int OD   = 256;
static constexpr int KBLK = 32;    // PROVEN best tile (r12/r16: ~116us; KBLK=64 regressed)

// 128B-row XOR swizzle (prep LDS tiles)
#define RSWZ(row, cb) ((((row) << 7)) + ((cb) ^ (((row) & 7) << 4)))

__device__ __forceinline__ f16x8 cvt8(const float4 a, const float4 b) {
    f16x8 r;
    r[0] = (_Float16)a.x; r[1] = (_Float16)a.y; r[2] = (_Float16)a.z; r[3] = (_Float16)a.w;
    r[4] = (_Float16)b.x; r[5] = (_Float16)b.y; r[6] = (_Float16)b.z; r[7] = (_Float16)b.w;
    return r;
}

__device__ __forceinline__ uint32_t pkh2(float x, float y) {
    union { _Float16 h[2]; uint32_t u; } z;
    z.h[0] = (_Float16)x; z.h[1] = (_Float16)y;
    return z.u;
}

// ---------------------------------------------------------------------------
// Setup (fused wcvt + compact_mask, block-role dispatch):
//  bid <  128: convert theta/phi weights to f16 (wf[sel][o][c]).
//  bid >= 128: per-batch ordered mask compaction (idx/pos/nbArr) + zero the
//              per-(b,qt) combine flags (graph replays need re-zeroing).
// ---------------------------------------------------------------------------
__global__ __launch_bounds__(256)
void setup(const float* __restrict__ thw, const float* __restrict__ phw,
           _Float16* __restrict__ wf,
           const float* __restrict__ mask, int* __restrict__ idx,
           int* __restrict__ pos, int* __restrict__ nbArr,
           int* __restrict__ flags)
{
    __shared__ int cnt[256];
    __shared__ int pre[257];
    const int t = threadIdx.x;

    if (blockIdx.x < 128) {
        const int i = blockIdx.x * 256 + t;       // 32768 float4 units
        const float4 a = ((const float4*)thw)[i];
        const float4 b = ((const float4*)phw)[i];
        f16x4 ra, rb;
        ra[0] = (_Float16)a.x; ra[1] = (_Float16)a.y; ra[2] = (_Float16)a.z; ra[3] = (_Float16)a.w;
        rb[0] = (_Float16)b.x; rb[1] = (_Float16)b.y; rb[2] = (_Float16)b.z; rb[3] = (_Float16)b.w;
        *(f16x4*)(wf + (size_t)i * 4)          = ra;
        *(f16x4*)(wf + 131072 + (size_t)i * 4) = rb;
        return;
    }

    const int b = blockIdx.x - 128;
    if (t < 16) flags[b * 16 + t] = 0;
    const float* mb = mask + (size_t)b * NHW;
    const int base = t * 16;
    float mv[16];
    int c = 0;
    #pragma unroll
    for (int i = 0; i < 16; ++i) { mv[i] = mb[base + i]; c += (mv[i] != 0.0f); }
    cnt[t] = c;
    __syncthreads();
    if (t == 0) {
        int s = 0;
        for (int i = 0; i < 256; ++i) { pre[i] = s; s += cnt[i]; }
        pre[256] = s;
    }
    __syncthreads();
    int o = pre[t];
    #pragma unroll
    for (int i = 0; i < 16; ++i) {
        if (mv[i] != 0.0f) {
            idx[(size_t)b * NHW + o] = base + i;
            pos[(size_t)b * NHW + base + i] = o;
            ++o;
        } else {
            pos[(size_t)b * NHW + base + i] = -1;
        }
    }
    const int Nb = pre[256];
    const int Npad = (Nb + 63) & ~63;
    for (int k = Nb + t; k < Npad; k += 256) idx[(size_t)b * NHW + k] = 0;
    if (t == 0) { nbArr[b * 2] = Nb; nbArr[b * 2 + 1] = Npad >> 5; }
}

// ---------------------------------------------------------------------------
// Fused prep + gather_v (block-role dispatch on z):
//  z < 16 : prep GEMM. sel=0 (theta) -> linear Qws; sel=1 (phi) -> DIRECT
//           compacted+swizzled Kc at row pos[n] (skip masked rows).
//  z >= 16: gather V columns (b = z-16) into compacted, pre-swizzled Vc.
// grid (64, 24), block 256.
// ---------------------------------------------------------------------------
__global__ __launch_bounds__(256)
void prep_gather(const float* __restrict__ xq, const float* __restrict__ xs,
                 const _Float16* __restrict__ wf,
                 const float* __restrict__ thb, const float* __restrict__ phb,
                 const int* __restrict__ pos,
                 const float* __restrict__ emb, const int* __restrict__ idx,
                 const int* __restrict__ nbArr,
                 _Float16* __restrict__ Qws, _Float16* __restrict__ Kc,
                 _Float16* __restrict__ Vc)
{
    __shared__ __align__(16) char Xs[64 * 128];    // [n][c-chunk 64] f16, swizzled
    __shared__ __align__(16) char Ws[256 * 128];   // [o][c-chunk 64] f16, swizzled
    __shared__ int Ps[64];
    __shared__ int sidx[64];

    const int t    = threadIdx.x;
    const int z    = blockIdx.y;

    if (z >= 16) {
        // ---- gather_v role ----
        const int b = z - 16, k0 = blockIdx.x * 64;
        const int Nb = nbArr[b * 2];
        const int Npad = (Nb + 63) & ~63;
        if (k0 >= Npad) return;
        if (t < 64) sidx[t] = idx[(size_t)b * NHW + k0 + t];
        __syncthreads();
        const float* eb = emb + (size_t)b * OD * NHW;
        char* VcB = (char*)(Vc + (size_t)b * OD * NHW);
        #pragma unroll
        for (int r = 0; r < 8; ++r) {
            const int u = r * 256 + t;             // 256 o x 8 units
            const int o = u >> 3, uc = u & 7;
            const int chunk = uc >> 2, uin = uc & 3;
            float4 a, c;
            #pragma unroll
            for (int i = 0; i < 4; ++i) ((float*)&a)[i] = eb[(size_t)o * NHW + sidx[uc * 8 + i]];
            #pragma unroll
            for (int i = 0; i < 4; ++i) ((float*)&c)[i] = eb[(size_t)o * NHW + sidx[uc * 8 + 4 + i]];
            const f16x8 v = cvt8(a, c);
            *(f16x8*)(VcB + (size_t)o * (NHW * 2) + (size_t)k0 * 2 + chunk * 64
                          + ((uin ^ ((o >> 1) & 3)) * 16)) = v;
        }
        return;
    }

    // ---- prep GEMM role ----
    const int nt = blockIdx.x;
    const int b = z >> 1, sel = z & 1;
    const float* x        = (sel ? xs : xq) + (size_t)b * CIN * NHW;
    const _Float16* w     = wf + (size_t)sel * (OD * CIN);
    const float* bias     = sel ? phb : thb;
    const int n0 = nt * 64;

    const int lane = t & 63, wave = t >> 6;
    const int l16  = lane & 15, lh = lane >> 4;

    if (sel && t < 64) Ps[t] = pos[(size_t)b * NHW + n0 + t];

    f32x4 acc[4][4] = {};   // [oo][nn]: rows o = wave*64+oo*16+4lh+r, cols n = nn*16+l16

    for (int c0 = 0; c0 < CIN; c0 += 64) {
        #pragma unroll
        for (int rep = 0; rep < 4; ++rep) {
            const int ci = rep * 16 + (t >> 4);
            const int nl = (t & 15) * 4;
            const float4 v = *(const float4*)&x[(size_t)(c0 + ci) * NHW + n0 + nl];
            *(_Float16*)(Xs + RSWZ(nl + 0, ci * 2)) = (_Float16)v.x;
            *(_Float16*)(Xs + RSWZ(nl + 1, ci * 2)) = (_Float16)v.y;
            *(_Float16*)(Xs + RSWZ(nl + 2, ci * 2)) = (_Float16)v.z;
            *(_Float16*)(Xs + RSWZ(nl + 3, ci * 2)) = (_Float16)v.w;
        }
        #pragma unroll
        for (int r = 0; r < 8; ++r) {
            const int u = r * 256 + t;
            const int o = u >> 3, cs8 = (u & 7) * 8;
            const f16x8 v = *(const f16x8*)(w + (size_t)o * CIN + c0 + cs8);
            *(f16x8*)(Ws + RSWZ(o, cs8 * 2)) = v;
        }
        __syncthreads();

        #pragma unroll
        for (int kk = 0; kk < 2; ++kk) {
            f16x8 af[4];
            #pragma unroll
            for (int oo = 0; oo < 4; ++oo)
                af[oo] = *(const f16x8*)(Ws + RSWZ(wave * 64 + oo * 16 + l16, kk * 64 + lh * 16));
            #pragma unroll
            for (int nn = 0; nn < 4; ++nn) {
                const f16x8 bf = *(const f16x8*)(Xs + RSWZ(nn * 16 + l16, kk * 64 + lh * 16));
                #pragma unroll
                for (int oo = 0; oo < 4; ++oo)
                    acc[oo][nn] = MFMA16(af[oo], bf, acc[oo][nn]);
            }
        }
        __syncthreads();
    }

    if (!sel) {
        _Float16* out = Qws + (size_t)b * NHW * OD;
        #pragma unroll
        for (int oo = 0; oo < 4; ++oo) {
            const float4 bi = *(const float4*)&bias[wave * 64 + oo * 16 + lh * 4];
            #pragma unroll
            for (int nn = 0; nn < 4; ++nn) {
                f16x4 v;
                v[0] = (_Float16)(acc[oo][nn][0] + bi.x);
                v[1] = (_Float16)(acc[oo][nn][1] + bi.y);
                v[2] = (_Float16)(acc[oo][nn][2] + bi.z);
                v[3] = (_Float16)(acc[oo][nn][3] + bi.w);
                const int n = n0 + nn * 16 + l16;
                *(f16x4*)&out[(size_t)n * OD + wave * 64 + oo * 16 + lh * 4] = v;
            }
        }
    } else {
        char* KcB = (char*)(Kc + (size_t)b * NHW * OD);
        #pragma unroll
        for (int oo = 0; oo < 4; ++oo) {
            const float4 bi = *(const float4*)&bias[wave * 64 + oo * 16 + lh * 4];
            const int o = wave * 64 + oo * 16 + lh * 4;
            #pragma unroll
            for (int nn = 0; nn < 4; ++nn) {
                const int k = Ps[nn * 16 + l16];
                if (k >= 0) {
                    f16x4 v;
                    v[0] = (_Float16)(acc[oo][nn][0] + bi.x);
                    v[1] = (_Float16)(acc[oo][nn][1] + bi.y);
                    v[2] = (_Float16)(acc[oo][nn][2] + bi.z);
                    v[3] = (_Float16)(acc[oo][nn][3] + bi.w);
                    *(f16x4*)(KcB + (size_t)k * 512
                              + (((o >> 3) * 16) ^ ((k & 7) << 4))
                              + ((o >> 2) & 1) * 8) = v;
                }
            }
        }
    }
}

// ---------------------------------------------------------------------------
// Flash attention + FUSED COMBINE (last-arriver). Round-12/16 inner loop
// (proven), T5 setprio, KBLK=32, 8-wave blocks, dual q-group, split-j, DMA
// staging. After writing partials, each block fences + bumps the per-(b,qt)
// flag; the second-arriving block merges the stripe (canonical
// threadFenceReduction pattern; output independent of arrival order).
// grid 256: b=bid&7, u=bid>>3, qt=u>>1, half=u&1.
// ---------------------------------------------------------------------------
__device__ __forceinline__ void stage_dma(const char* __restrict__ Kb,
                                          const char* __restrict__ Vb,
                                          int j, int t, int wbase,
                                          char* Kld, char* Vld)
{
    typedef __attribute__((address_space(1))) const unsigned int gu32;
    typedef __attribute__((address_space(3))) unsigned int lu32;
    const char* kb = Kb + (size_t)j * (KBLK * 512);
    #pragma unroll
    for (int r = 0; r < 2; ++r) {
        __builtin_amdgcn_global_load_lds(
            (gu32*)(kb + (size_t)(r * 512 + t) * 16),
            (lu32*)(Kld + (r * 512 + wbase) * 16), 16, 0, 0);
    }
    #pragma unroll
    for (int r = 0; r < 2; ++r) {
        const int u = r * 512 + t, o = u >> 2, sl = u & 3;
        __builtin_amdgcn_global_load_lds(
            (gu32*)(Vb + (size_t)o * (NHW * 2) + (size_t)j * 64 + sl * 16),
            (lu32*)(Vld + (r * 512 + wbase) * 16), 16, 0, 0);
    }
}

__global__ __launch_bounds__(512, 2)
void flash_attn(const _Float16* __restrict__ Qws, const _Float16* __restrict__ Kc,
                const _Float16* __restrict__ Vc, const int* __restrict__ nbArr,
                _Float16* __restrict__ Op0, _Float16* __restrict__ Op1,
                float* __restrict__ Sarr, int* __restrict__ flags,
                float* __restrict__ outp)
{
    const int bid = blockIdx.x;
    const int b = bid & 7, u = bid >> 3;
    const int qt = u >> 1, half = u & 1;
    const int t = threadIdx.x, lane = t & 63, wave = t >> 6;
    const int l16 = lane & 15, lh = lane >> 4;
    const int wbase = wave << 6;

    __shared__ __align__(16) char Kl[2][KBLK * 512];   // 2 x 16 KB (swizzled)
    __shared__ __align__(16) char Vl[2][OD * 64];      // 2 x 16 KB (swizzled)
    __shared__ int sflag;

    const _Float16* Qb = Qws + (size_t)b * NHW * OD;
    const char* Kb = (const char*)(Kc + (size_t)b * NHW * OD);
    const char* Vb = (const char*)(Vc + (size_t)b * OD * NHW);
    const int Nb = nbArr[b * 2];
    const int nt = nbArr[b * 2 + 1];
    const int nth = (nt + 1) >> 1;
    const int j0 = half ? nth : 0;
    const int j1 = half ? nt : nth;
    const int nl = j1 - j0;

    // Q fragments, 2 groups: lane l16 = q-row within group
    f16x8 qf[8][2];
    #pragma unroll
    for (int g = 0; g < 2; ++g) {
        const _Float16* qrow = Qb
            + (size_t)(qt * 256 + wave * 32 + g * 16 + l16) * OD + lh * 8;
        #pragma unroll
        for (int kk = 0; kk < 8; ++kk) qf[kk][g] = *(const f16x8*)(qrow + kk * 32);
    }

    f32x4 accO[16][2] = {};          // D[o][q] per group
    float M0 = -INFINITY, L0 = 0.f;
    float M1 = -INFINITY, L1 = 0.f;

    // prologue: DMA tile j0 into buf 0; barrier drains vmcnt
    stage_dma(Kb, Vb, j0, t, wbase, Kl[0], Vl[0]);
    __syncthreads();

    #pragma unroll 1
    for (int i = 0; i < nl; ++i) {
        const int jt = j0 + i;
        const int cur = i & 1;
        // ---- issue DMA for next tile into other buffer
        if (i + 1 < nl) stage_dma(Kb, Vb, jt + 1, t, wbase, Kl[cur ^ 1], Vl[cur ^ 1]);

        // ---- S' = K Q^T (swapped): each kf read feeds BOTH q-groups
        f32x4 S[2][2] = {};
        __builtin_amdgcn_s_setprio(1);
        #pragma unroll
        for (int ct = 0; ct < 2; ++ct) {
            const int row = ct * 16 + l16;
            #pragma unroll
            for (int kk = 0; kk < 8; ++kk) {
                const f16x8 kf = *(const f16x8*)(Kl[cur] + row * 512
                                     + ((kk * 64 + lh * 16) ^ ((row & 7) << 4)));
                S[ct][0] = MFMA16(kf, qf[kk][0], S[ct][0]);
                S[ct][1] = MFMA16(kf, qf[kk][1], S[ct][1]);
            }
        }
        __builtin_amdgcn_s_setprio(0);

        // ---- logits
        const bool tail = (jt * 32 + 32 > Nb);
        float lg[8][2];
        #pragma unroll
        for (int ct = 0; ct < 2; ++ct)
            #pragma unroll
            for (int r = 0; r < 4; ++r) {
                float v0 = S[ct][0][r] * 0.25f;
                float v1 = S[ct][1][r] * 0.25f;
                if (tail) {
                    const int kg = jt * 32 + ct * 16 + lh * 4 + r;
                    if (kg >= Nb) { v0 = -1e30f; v1 = -1e30f; }
                }
                lg[ct * 4 + r][0] = v0;
                lg[ct * 4 + r][1] = v1;
            }

        // ---- per-lane row max (per group)
        float m80 = lg[0][0], m81 = lg[0][1];
        #pragma unroll
        for (int i2 = 1; i2 < 8; ++i2) { m80 = fmaxf(m80, lg[i2][0]); m81 = fmaxf(m81, lg[i2][1]); }
        m80 = fmaxf(m80, __shfl_xor(m80, 16));
        m80 = fmaxf(m80, __shfl_xor(m80, 32));
        m81 = fmaxf(m81, __shfl_xor(m81, 16));
        m81 = fmaxf(m81, __shfl_xor(m81, 32));

        // ---- deferred rescale (THR=8)
        if (__any((m80 > M0 + 8.0f) || (m81 > M1 + 8.0f))) {
            const float nm0 = fmaxf(M0, m80), nm1 = fmaxf(M1, m81);
            const float f0 = __expf(M0 - nm0), f1 = __expf(M1 - nm1);
            M0 = nm0; L0 *= f0; M1 = nm1; L1 *= f1;
            #pragma unroll
            for (int oo = 0; oo < 16; ++oo)
                #pragma unroll
                for (int r = 0; r < 4; ++r) {
                    accO[oo][0][r] *= f0;
                    accO[oo][1][r] *= f1;
                }
        }

        // ---- P = exp(lg - M), row sums (per group), in-place over lg
        float s0 = 0.f, s1 = 0.f;
        #pragma unroll
        for (int i2 = 0; i2 < 8; ++i2) {
            lg[i2][0] = __expf(lg[i2][0] - M0); s0 += lg[i2][0];
            lg[i2][1] = __expf(lg[i2][1] - M1); s1 += lg[i2][1];
        }
        s0 += __shfl_xor(s0, 16); s0 += __shfl_xor(s0, 32); L0 += s0;
        s1 += __shfl_xor(s1, 16); s1 += __shfl_xor(s1, 32); L1 += s1;

        // ---- re-fragment P per group (pull both halves, select by dest lh&2)
        const int src0 = l16 + (((2 * lh) & 3) << 4);
        const int src1 = src0 + 16;
        const bool hi = (lh & 2) != 0;
        f16x8 pf[2];
        #pragma unroll
        for (int g = 0; g < 2; ++g) {
            const uint32_t ps0 = pkh2(lg[0][g], lg[1][g]), ps1 = pkh2(lg[2][g], lg[3][g]);
            const uint32_t ps2 = pkh2(lg[4][g], lg[5][g]), ps3 = pkh2(lg[6][g], lg[7][g]);
            const uint32_t a0 = __shfl(ps0, src0), a2 = __shfl(ps2, src0);
            const uint32_t a1 = __shfl(ps1, src0), a3 = __shfl(ps3, src0);
            const uint32_t b0 = __shfl(ps0, src1), b2 = __shfl(ps2, src1);
            const uint32_t b1 = __shfl(ps1, src1), b3 = __shfl(ps3, src1);
            union { uint32_t u[4]; f16x8 v; } pu;
            pu.u[0] = hi ? a2 : a0;
            pu.u[1] = hi ? a3 : a1;
            pu.u[2] = hi ? b2 : b0;
            pu.u[3] = hi ? b3 : b1;
            pf[g] = pu.v;
        }

        // ---- O += V^T P : each vf read feeds BOTH q-groups
        __builtin_amdgcn_s_setprio(1);
        #pragma unroll
        for (int oo = 0; oo < 16; ++oo) {
            const int o = oo * 16 + l16;
            const f16x8 vf = *(const f16x8*)(Vl[cur] + o * 64
                                 + ((lh * 16) ^ (((o >> 1) & 3) << 4)));
            accO[oo][0] = MFMA16(vf, pf[0], accO[oo][0]);
            accO[oo][1] = MFMA16(vf, pf[1], accO[oo][1]);
        }
        __builtin_amdgcn_s_setprio(0);
        __syncthreads();
    }

    // ---- epilogue: normalized partial (f16) + S = M + ln L (f32)
    _Float16* Od = half ? Op1 : Op0;
    float*    Sd = Sarr + (size_t)half * (BN * NHW) + (size_t)b * NHW;
    const float rl0 = 1.0f / fmaxf(L0, 1e-30f);
    const float rl1 = 1.0f / fmaxf(L1, 1e-30f);
    const int n0 = qt * 256 + wave * 32 + l16;
    if (lh == 0) {
        Sd[n0]      = (L0 > 0.f) ? (M0 + __logf(L0)) : -1e30f;
        Sd[n0 + 16] = (L1 > 0.f) ? (M1 + __logf(L1)) : -1e30f;
    }
    #pragma unroll
    for (int oo = 0; oo < 16; ++oo) {
        #pragma unroll
        for (int r = 0; r < 4; ++r) {
            const int o = oo * 16 + lh * 4 + r;
            _Float16* row = Od + ((size_t)b * OD + o) * NHW;
            row[n0]      = (_Float16)(accO[oo][0][r] * rl0);
            row[n0 + 16] = (_Float16)(accO[oo][1][r] * rl1);
        }
    }

    // ---- fused combine: second-arriving half merges this (b,qt) stripe
    __threadfence();                     // release this thread's partial stores
    __syncthreads();                     // all threads' fences done
    if (t == 0) sflag = atomicAdd(&flags[b * 16 + qt], 1);
    __syncthreads();
    if (sflag == 1) {
        __threadfence();                 // acquire: partner's stores visible
        const float* S0 = Sarr + (size_t)b * NHW;
        const float* S1 = Sarr + (size_t)BN * NHW + (size_t)b * NHW;
        const int nc = qt * 256 + (t & 31) * 8;
        const int ob = t >> 5;           // 0..15
        float a0[8], a1[8];
        #pragma unroll
        for (int i = 0; i < 8; ++i) {
            const float s0 = S0[nc + i], s1 = S1[nc + i];
            const float sm = fmaxf(s0, s1);
            const float w0 = __expf(s0 - sm), w1 = __expf(s1 - sm);
            const float inv = 1.0f / (w0 + w1);
            a0[i] = w0 * inv; a1[i] = w1 * inv;
        }
        for (int o = ob; o < OD; o += 16) {
            const size_t base = ((size_t)b * OD + o) * NHW + nc;
            const f16x8 uu = *(const f16x8*)(Op0 + base);
            const f16x8 vv = *(const f16x8*)(Op1 + base);
            float4 r0, r1;
            r0.x = a0[0] * (float)uu[0] + a1[0] * (float)vv[0];
            r0.y = a0[1] * (float)uu[1] + a1[1] * (float)vv[1];
            r0.z = a0[2] * (float)uu[2] + a1[2] * (float)vv[2];
            r0.w = a0[3] * (float)uu[3] + a1[3] * (float)vv[3];
            r1.x = a0[4] * (float)uu[4] + a1[4] * (float)vv[4];
            r1.y = a0[5] * (float)uu[5] + a1[5] * (float)vv[5];
            r1.z = a0[6] * (float)uu[6] + a1[6] * (float)vv[6];
            r1.w = a0[7] * (float)uu[7] + a1[7] * (float)vv[7];
            *(float4*)&outp[base]     = r0;
            *(float4*)&outp[base + 4] = r1;
        }
    }
}

extern "C" void kernel_launch(void* const* d_in, const int* in_sizes, int n_in,
                              void* d_out, int out_size, void* d_ws, size_t ws_size,
                              hipStream_t stream) {
    const float* xq   = (const float*)d_in[0];
    const float* xs   = (const float*)d_in[1];
    const float* emb  = (const float*)d_in[2];
    const float* mask = (const float*)d_in[3];
    const float* thw  = (const float*)d_in[4];
    const float* thb  = (const float*)d_in[5];
    const float* phw  = (const float*)d_in[6];
    const float* phb  = (const float*)d_in[7];
    float* out = (float*)d_out;

    const size_t szT = (size_t)BN * NHW * OD;   // elements per f16 tensor
    _Float16* Qws = (_Float16*)d_ws;
    _Float16* Op0 = Qws + szT;
    _Float16* Kc  = Op0 + szT;
    _Float16* Vc  = Kc + szT;
    _Float16* wf  = Vc + szT;                   // 2*256*512 f16
    int* idxArr   = (int*)(wf + 2 * OD * CIN);
    int* nbArr    = idxArr + (size_t)BN * NHW;
    int* posArr   = nbArr + 16;
    _Float16* Op1 = (_Float16*)(posArr + (size_t)BN * NHW);
    float* Sarr   = (float*)(Op1 + szT);        // [2][BN][NHW]
    int* flags    = (int*)(Sarr + 2 * (size_t)BN * NHW);  // [BN*16]

    setup<<<dim3(136), 256, 0, stream>>>(thw, phw, wf, mask, idxArr, posArr, nbArr, flags);
    prep_gather<<<dim3(64, 24), 256, 0, stream>>>(xq, xs, wf, thb, phb, posArr,
                                                  emb, idxArr, nbArr, Qws, Kc, Vc);
    flash_attn<<<dim3(256), 512, 0, stream>>>(Qws, Kc, Vc, nbArr, Op0, Op1, Sarr,
                                              flags, out);
}

// Round 19
// 185.615 us; speedup vs baseline: 1.4385x; 1.4385x over previous
//
#include <hip/hip_runtime.h>
#include <hip/hip_fp16.h>
#include <stdint.h>

typedef _Float16 f16x8 __attribute__((ext_vector_type(8)));
typedef _Float16 f16x4 __attribute__((ext_vector_type(4)));
typedef float    f32x4 __attribute__((ext_vector_type(4)));

#define MFMA16(a, b, c) __builtin_amdgcn_mfma_f32_16x16x32_f16(a, b, c, 0, 0, 0)

static constexpr int BN   = 8;
static constexpr int CIN  = 512;
static constexpr int NHW  = 4096;
static constexpr int OD   = 256;
static constexpr int KBLK = 32;    // PROVEN best tile (r12/r16: ~116us; KBLK=64 regressed)

// 128B-row XOR swizzle (prep LDS tiles)
#define RSWZ(row, cb) ((((row) << 7)) + ((cb) ^ (((row) & 7) << 4)))

__device__ __forceinline__ f16x8 cvt8(const float4 a, const float4 b) {
    f16x8 r;
    r[0] = (_Float16)a.x; r[1] = (_Float16)a.y; r[2] = (_Float16)a.z; r[3] = (_Float16)a.w;
    r[4] = (_Float16)b.x; r[5] = (_Float16)b.y; r[6] = (_Float16)b.z; r[7] = (_Float16)b.w;
    return r;
}

__device__ __forceinline__ uint32_t pkh2(float x, float y) {
    union { _Float16 h[2]; uint32_t u; } z;
    z.h[0] = (_Float16)x; z.h[1] = (_Float16)y;
    return z.u;
}

// ---------------------------------------------------------------------------
// Setup (fused wcvt + compact_mask, block-role dispatch):
//  bid <  128: convert theta/phi weights to f16 (wf[sel][o][c]).
//  bid >= 128: per-batch ordered mask compaction (idx/pos/nbArr).
// ---------------------------------------------------------------------------
__global__ __launch_bounds__(256)
void setup(const float* __restrict__ thw, const float* __restrict__ phw,
           _Float16* __restrict__ wf,
           const float* __restrict__ mask, int* __restrict__ idx,
           int* __restrict__ pos, int* __restrict__ nbArr)
{
    __shared__ int cnt[256];
    __shared__ int pre[257];
    const int t = threadIdx.x;

    if (blockIdx.x < 128) {
        const int i = blockIdx.x * 256 + t;       // 32768 float4 units
        const float4 a = ((const float4*)thw)[i];
        const float4 b = ((const float4*)phw)[i];
        f16x4 ra, rb;
        ra[0] = (_Float16)a.x; ra[1] = (_Float16)a.y; ra[2] = (_Float16)a.z; ra[3] = (_Float16)a.w;
        rb[0] = (_Float16)b.x; rb[1] = (_Float16)b.y; rb[2] = (_Float16)b.z; rb[3] = (_Float16)b.w;
        *(f16x4*)(wf + (size_t)i * 4)          = ra;
        *(f16x4*)(wf + 131072 + (size_t)i * 4) = rb;
        return;
    }

    const int b = blockIdx.x - 128;
    const float* mb = mask + (size_t)b * NHW;
    const int base = t * 16;
    float mv[16];
    int c = 0;
    #pragma unroll
    for (int i = 0; i < 16; ++i) { mv[i] = mb[base + i]; c += (mv[i] != 0.0f); }
    cnt[t] = c;
    __syncthreads();
    if (t == 0) {
        int s = 0;
        for (int i = 0; i < 256; ++i) { pre[i] = s; s += cnt[i]; }
        pre[256] = s;
    }
    __syncthreads();
    int o = pre[t];
    #pragma unroll
    for (int i = 0; i < 16; ++i) {
        if (mv[i] != 0.0f) {
            idx[(size_t)b * NHW + o] = base + i;
            pos[(size_t)b * NHW + base + i] = o;
            ++o;
        } else {
            pos[(size_t)b * NHW + base + i] = -1;
        }
    }
    const int Nb = pre[256];
    const int Npad = (Nb + 63) & ~63;
    for (int k = Nb + t; k < Npad; k += 256) idx[(size_t)b * NHW + k] = 0;
    if (t == 0) { nbArr[b * 2] = Nb; nbArr[b * 2 + 1] = Npad >> 5; }
}

// ---------------------------------------------------------------------------
// Fused prep + gather_v (block-role dispatch on z):
//  z < 16 : prep GEMM. sel=0 (theta) -> linear Qws; sel=1 (phi) -> DIRECT
//           compacted+swizzled Kc at row pos[n] (skip masked rows).
//  z >= 16: gather V columns (b = z-16) into compacted, pre-swizzled Vc.
// grid (64, 24), block 256.
// ---------------------------------------------------------------------------
__global__ __launch_bounds__(256)
void prep_gather(const float* __restrict__ xq, const float* __restrict__ xs,
                 const _Float16* __restrict__ wf,
                 const float* __restrict__ thb, const float* __restrict__ phb,
                 const int* __restrict__ pos,
                 const float* __restrict__ emb, const int* __restrict__ idx,
                 const int* __restrict__ nbArr,
                 _Float16* __restrict__ Qws, _Float16* __restrict__ Kc,
                 _Float16* __restrict__ Vc)
{
    __shared__ __align__(16) char Xs[64 * 128];    // [n][c-chunk 64] f16, swizzled
    __shared__ __align__(16) char Ws[256 * 128];   // [o][c-chunk 64] f16, swizzled
    __shared__ int Ps[64];
    __shared__ int sidx[64];

    const int t    = threadIdx.x;
    const int z    = blockIdx.y;

    if (z >= 16) {
        // ---- gather_v role ----
        const int b = z - 16, k0 = blockIdx.x * 64;
        const int Nb = nbArr[b * 2];
        const int Npad = (Nb + 63) & ~63;
        if (k0 >= Npad) return;
        if (t < 64) sidx[t] = idx[(size_t)b * NHW + k0 + t];
        __syncthreads();
        const float* eb = emb + (size_t)b * OD * NHW;
        char* VcB = (char*)(Vc + (size_t)b * OD * NHW);
        #pragma unroll
        for (int r = 0; r < 8; ++r) {
            const int u = r * 256 + t;             // 256 o x 8 units
            const int o = u >> 3, uc = u & 7;
            const int chunk = uc >> 2, uin = uc & 3;
            float4 a, c;
            #pragma unroll
            for (int i = 0; i < 4; ++i) ((float*)&a)[i] = eb[(size_t)o * NHW + sidx[uc * 8 + i]];
            #pragma unroll
            for (int i = 0; i < 4; ++i) ((float*)&c)[i] = eb[(size_t)o * NHW + sidx[uc * 8 + 4 + i]];
            const f16x8 v = cvt8(a, c);
            *(f16x8*)(VcB + (size_t)o * (NHW * 2) + (size_t)k0 * 2 + chunk * 64
                          + ((uin ^ ((o >> 1) & 3)) * 16)) = v;
        }
        return;
    }

    // ---- prep GEMM role ----
    const int nt = blockIdx.x;
    const int b = z >> 1, sel = z & 1;
    const float* x        = (sel ? xs : xq) + (size_t)b * CIN * NHW;
    const _Float16* w     = wf + (size_t)sel * (OD * CIN);
    const float* bias     = sel ? phb : thb;
    const int n0 = nt * 64;

    const int lane = t & 63, wave = t >> 6;
    const int l16  = lane & 15, lh = lane >> 4;

    if (sel && t < 64) Ps[t] = pos[(size_t)b * NHW + n0 + t];

    f32x4 acc[4][4] = {};   // [oo][nn]: rows o = wave*64+oo*16+4lh+r, cols n = nn*16+l16

    for (int c0 = 0; c0 < CIN; c0 += 64) {
        #pragma unroll
        for (int rep = 0; rep < 4; ++rep) {
            const int ci = rep * 16 + (t >> 4);
            const int nl = (t & 15) * 4;
            const float4 v = *(const float4*)&x[(size_t)(c0 + ci) * NHW + n0 + nl];
            *(_Float16*)(Xs + RSWZ(nl + 0, ci * 2)) = (_Float16)v.x;
            *(_Float16*)(Xs + RSWZ(nl + 1, ci * 2)) = (_Float16)v.y;
            *(_Float16*)(Xs + RSWZ(nl + 2, ci * 2)) = (_Float16)v.z;
            *(_Float16*)(Xs + RSWZ(nl + 3, ci * 2)) = (_Float16)v.w;
        }
        #pragma unroll
        for (int r = 0; r < 8; ++r) {
            const int u = r * 256 + t;
            const int o = u >> 3, cs8 = (u & 7) * 8;
            const f16x8 v = *(const f16x8*)(w + (size_t)o * CIN + c0 + cs8);
            *(f16x8*)(Ws + RSWZ(o, cs8 * 2)) = v;
        }
        __syncthreads();

        #pragma unroll
        for (int kk = 0; kk < 2; ++kk) {
            f16x8 af[4];
            #pragma unroll
            for (int oo = 0; oo < 4; ++oo)
                af[oo] = *(const f16x8*)(Ws + RSWZ(wave * 64 + oo * 16 + l16, kk * 64 + lh * 16));
            #pragma unroll
            for (int nn = 0; nn < 4; ++nn) {
                const f16x8 bf = *(const f16x8*)(Xs + RSWZ(nn * 16 + l16, kk * 64 + lh * 16));
                #pragma unroll
                for (int oo = 0; oo < 4; ++oo)
                    acc[oo][nn] = MFMA16(af[oo], bf, acc[oo][nn]);
            }
        }
        __syncthreads();
    }

    if (!sel) {
        _Float16* out = Qws + (size_t)b * NHW * OD;
        #pragma unroll
        for (int oo = 0; oo < 4; ++oo) {
            const float4 bi = *(const float4*)&bias[wave * 64 + oo * 16 + lh * 4];
            #pragma unroll
            for (int nn = 0; nn < 4; ++nn) {
                f16x4 v;
                v[0] = (_Float16)(acc[oo][nn][0] + bi.x);
                v[1] = (_Float16)(acc[oo][nn][1] + bi.y);
                v[2] = (_Float16)(acc[oo][nn][2] + bi.z);
                v[3] = (_Float16)(acc[oo][nn][3] + bi.w);
                const int n = n0 + nn * 16 + l16;
                *(f16x4*)&out[(size_t)n * OD + wave * 64 + oo * 16 + lh * 4] = v;
            }
        }
    } else {
        char* KcB = (char*)(Kc + (size_t)b * NHW * OD);
        #pragma unroll
        for (int oo = 0; oo < 4; ++oo) {
            const float4 bi = *(const float4*)&bias[wave * 64 + oo * 16 + lh * 4];
            const int o = wave * 64 + oo * 16 + lh * 4;
            #pragma unroll
            for (int nn = 0; nn < 4; ++nn) {
                const int k = Ps[nn * 16 + l16];
                if (k >= 0) {
                    f16x4 v;
                    v[0] = (_Float16)(acc[oo][nn][0] + bi.x);
                    v[1] = (_Float16)(acc[oo][nn][1] + bi.y);
                    v[2] = (_Float16)(acc[oo][nn][2] + bi.z);
                    v[3] = (_Float16)(acc[oo][nn][3] + bi.w);
                    *(f16x4*)(KcB + (size_t)k * 512
                              + (((o >> 3) * 16) ^ ((k & 7) << 4))
                              + ((o >> 2) & 1) * 8) = v;
                }
            }
        }
    }
}

// ---------------------------------------------------------------------------
// Flash attention — round-12/16 structure + T5 setprio (proven 112.9us).
// KBLK=32, 8-wave blocks, dual q-group, split-j, DMA staging.
// grid 256: b=bid&7, u=bid>>3, qt=u>>1, half=u&1.
// LDS 64 KB, regs 128 arch + 128 acc -> 2 waves/SIMD (8 waves/CU).
// ---------------------------------------------------------------------------
__device__ __forceinline__ void stage_dma(const char* __restrict__ Kb,
                                          const char* __restrict__ Vb,
                                          int j, int t, int wbase,
                                          char* Kld, char* Vld)
{
    typedef __attribute__((address_space(1))) const unsigned int gu32;
    typedef __attribute__((address_space(3))) unsigned int lu32;
    const char* kb = Kb + (size_t)j * (KBLK * 512);
    #pragma unroll
    for (int r = 0; r < 2; ++r) {
        __builtin_amdgcn_global_load_lds(
            (gu32*)(kb + (size_t)(r * 512 + t) * 16),
            (lu32*)(Kld + (r * 512 + wbase) * 16), 16, 0, 0);
    }
    #pragma unroll
    for (int r = 0; r < 2; ++r) {
        const int u = r * 512 + t, o = u >> 2, sl = u & 3;
        __builtin_amdgcn_global_load_lds(
            (gu32*)(Vb + (size_t)o * (NHW * 2) + (size_t)j * 64 + sl * 16),
            (lu32*)(Vld + (r * 512 + wbase) * 16), 16, 0, 0);
    }
}

__global__ __launch_bounds__(512, 2)
void flash_attn(const _Float16* __restrict__ Qws, const _Float16* __restrict__ Kc,
                const _Float16* __restrict__ Vc, const int* __restrict__ nbArr,
                _Float16* __restrict__ Op0, _Float16* __restrict__ Op1,
                float* __restrict__ Sarr)
{
    const int bid = blockIdx.x;
    const int b = bid & 7, u = bid >> 3;
    const int qt = u >> 1, half = u & 1;
    const int t = threadIdx.x, lane = t & 63, wave = t >> 6;
    const int l16 = lane & 15, lh = lane >> 4;
    const int wbase = wave << 6;

    __shared__ __align__(16) char Kl[2][KBLK * 512];   // 2 x 16 KB (swizzled)
    __shared__ __align__(16) char Vl[2][OD * 64];      // 2 x 16 KB (swizzled)

    const _Float16* Qb = Qws + (size_t)b * NHW * OD;
    const char* Kb = (const char*)(Kc + (size_t)b * NHW * OD);
    const char* Vb = (const char*)(Vc + (size_t)b * OD * NHW);
    const int Nb = nbArr[b * 2];
    const int nt = nbArr[b * 2 + 1];
    const int nth = (nt + 1) >> 1;
    const int j0 = half ? nth : 0;
    const int j1 = half ? nt : nth;
    const int nl = j1 - j0;

    // Q fragments, 2 groups: lane l16 = q-row within group
    f16x8 qf[8][2];
    #pragma unroll
    for (int g = 0; g < 2; ++g) {
        const _Float16* qrow = Qb
            + (size_t)(qt * 256 + wave * 32 + g * 16 + l16) * OD + lh * 8;
        #pragma unroll
        for (int kk = 0; kk < 8; ++kk) qf[kk][g] = *(const f16x8*)(qrow + kk * 32);
    }

    f32x4 accO[16][2] = {};          // D[o][q] per group
    float M0 = -INFINITY, L0 = 0.f;
    float M1 = -INFINITY, L1 = 0.f;

    // prologue: DMA tile j0 into buf 0; barrier drains vmcnt
    stage_dma(Kb, Vb, j0, t, wbase, Kl[0], Vl[0]);
    __syncthreads();

    #pragma unroll 1
    for (int i = 0; i < nl; ++i) {
        const int jt = j0 + i;
        const int cur = i & 1;
        // ---- issue DMA for next tile into other buffer
        if (i + 1 < nl) stage_dma(Kb, Vb, jt + 1, t, wbase, Kl[cur ^ 1], Vl[cur ^ 1]);

        // ---- S' = K Q^T (swapped): each kf read feeds BOTH q-groups
        f32x4 S[2][2] = {};
        __builtin_amdgcn_s_setprio(1);
        #pragma unroll
        for (int ct = 0; ct < 2; ++ct) {
            const int row = ct * 16 + l16;
            #pragma unroll
            for (int kk = 0; kk < 8; ++kk) {
                const f16x8 kf = *(const f16x8*)(Kl[cur] + row * 512
                                     + ((kk * 64 + lh * 16) ^ ((row & 7) << 4)));
                S[ct][0] = MFMA16(kf, qf[kk][0], S[ct][0]);
                S[ct][1] = MFMA16(kf, qf[kk][1], S[ct][1]);
            }
        }
        __builtin_amdgcn_s_setprio(0);

        // ---- logits
        const bool tail = (jt * 32 + 32 > Nb);
        float lg[8][2];
        #pragma unroll
        for (int ct = 0; ct < 2; ++ct)
            #pragma unroll
            for (int r = 0; r < 4; ++r) {
                float v0 = S[ct][0][r] * 0.25f;
                float v1 = S[ct][1][r] * 0.25f;
                if (tail) {
                    const int kg = jt * 32 + ct * 16 + lh * 4 + r;
                    if (kg >= Nb) { v0 = -1e30f; v1 = -1e30f; }
                }
                lg[ct * 4 + r][0] = v0;
                lg[ct * 4 + r][1] = v1;
            }

        // ---- per-lane row max (per group)
        float m80 = lg[0][0], m81 = lg[0][1];
        #pragma unroll
        for (int i2 = 1; i2 < 8; ++i2) { m80 = fmaxf(m80, lg[i2][0]); m81 = fmaxf(m81, lg[i2][1]); }
        m80 = fmaxf(m80, __shfl_xor(m80, 16));
        m80 = fmaxf(m80, __shfl_xor(m80, 32));
        m81 = fmaxf(m81, __shfl_xor(m81, 16));
        m81 = fmaxf(m81, __shfl_xor(m81, 32));

        // ---- deferred rescale (THR=8)
        if (__any((m80 > M0 + 8.0f) || (m81 > M1 + 8.0f))) {
            const float nm0 = fmaxf(M0, m80), nm1 = fmaxf(M1, m81);
            const float f0 = __expf(M0 - nm0), f1 = __expf(M1 - nm1);
            M0 = nm0; L0 *= f0; M1 = nm1; L1 *= f1;
            #pragma unroll
            for (int oo = 0; oo < 16; ++oo)
                #pragma unroll
                for (int r = 0; r < 4; ++r) {
                    accO[oo][0][r] *= f0;
                    accO[oo][1][r] *= f1;
                }
        }

        // ---- P = exp(lg - M), row sums (per group), in-place over lg
        float s0 = 0.f, s1 = 0.f;
        #pragma unroll
        for (int i2 = 0; i2 < 8; ++i2) {
            lg[i2][0] = __expf(lg[i2][0] - M0); s0 += lg[i2][0];
            lg[i2][1] = __expf(lg[i2][1] - M1); s1 += lg[i2][1];
        }
        s0 += __shfl_xor(s0, 16); s0 += __shfl_xor(s0, 32); L0 += s0;
        s1 += __shfl_xor(s1, 16); s1 += __shfl_xor(s1, 32); L1 += s1;

        // ---- re-fragment P per group (pull both halves, select by dest lh&2)
        const int src0 = l16 + (((2 * lh) & 3) << 4);
        const int src1 = src0 + 16;
        const bool hi = (lh & 2) != 0;
        f16x8 pf[2];
        #pragma unroll
        for (int g = 0; g < 2; ++g) {
            const uint32_t ps0 = pkh2(lg[0][g], lg[1][g]), ps1 = pkh2(lg[2][g], lg[3][g]);
            const uint32_t ps2 = pkh2(lg[4][g], lg[5][g]), ps3 = pkh2(lg[6][g], lg[7][g]);
            const uint32_t a0 = __shfl(ps0, src0), a2 = __shfl(ps2, src0);
            const uint32_t a1 = __shfl(ps1, src0), a3 = __shfl(ps3, src0);
            const uint32_t b0 = __shfl(ps0, src1), b2 = __shfl(ps2, src1);
            const uint32_t b1 = __shfl(ps1, src1), b3 = __shfl(ps3, src1);
            union { uint32_t u[4]; f16x8 v; } pu;
            pu.u[0] = hi ? a2 : a0;
            pu.u[1] = hi ? a3 : a1;
            pu.u[2] = hi ? b2 : b0;
            pu.u[3] = hi ? b3 : b1;
            pf[g] = pu.v;
        }

        // ---- O += V^T P : each vf read feeds BOTH q-groups
        __builtin_amdgcn_s_setprio(1);
        #pragma unroll
        for (int oo = 0; oo < 16; ++oo) {
            const int o = oo * 16 + l16;
            const f16x8 vf = *(const f16x8*)(Vl[cur] + o * 64
                                 + ((lh * 16) ^ (((o >> 1) & 3) << 4)));
            accO[oo][0] = MFMA16(vf, pf[0], accO[oo][0]);
            accO[oo][1] = MFMA16(vf, pf[1], accO[oo][1]);
        }
        __builtin_amdgcn_s_setprio(0);
        __syncthreads();
    }

    // ---- epilogue: normalized partial (f16) + S = M + ln L (f32)
    _Float16* Od = half ? Op1 : Op0;
    float*    Sd = Sarr + (size_t)half * (BN * NHW) + (size_t)b * NHW;
    const float rl0 = 1.0f / fmaxf(L0, 1e-30f);
    const float rl1 = 1.0f / fmaxf(L1, 1e-30f);
    const int n0 = qt * 256 + wave * 32 + l16;
    if (lh == 0) {
        Sd[n0]      = (L0 > 0.f) ? (M0 + __logf(L0)) : -1e30f;
        Sd[n0 + 16] = (L1 > 0.f) ? (M1 + __logf(L1)) : -1e30f;
    }
    #pragma unroll
    for (int oo = 0; oo < 16; ++oo) {
        #pragma unroll
        for (int r = 0; r < 4; ++r) {
            const int o = oo * 16 + lh * 4 + r;
            _Float16* row = Od + ((size_t)b * OD + o) * NHW;
            row[n0]      = (_Float16)(accO[oo][0][r] * rl0);
            row[n0 + 16] = (_Float16)(accO[oo][1][r] * rl1);
        }
    }
}

// ---------------------------------------------------------------------------
// Combine: out = (w0*O0 + w1*O1)/(w0+w1), w_h = exp(S_h - max(S0,S1)).
// grid (64 n-tiles, 8 b), block 256. Thread: 8-n chunk x 8 o-rows.
// ---------------------------------------------------------------------------
__global__ __launch_bounds__(256)
void combine(const _Float16* __restrict__ Op0, const _Float16* __restrict__ Op1,
             const float* __restrict__ Sarr, float* __restrict__ outp)
{
    const int b = blockIdx.y;
    const int n0 = blockIdx.x * 64;
    const int t = threadIdx.x;
    const int nc = n0 + (t & 7) * 8;
    const int ob = t >> 3;          // 0..31
    const float* S0 = Sarr + (size_t)b * NHW;
    const float* S1 = Sarr + (size_t)BN * NHW + (size_t)b * NHW;

    float a0[8], a1[8];
    #pragma unroll
    for (int i = 0; i < 8; ++i) {
        const float s0 = S0[nc + i], s1 = S1[nc + i];
        const float sm = fmaxf(s0, s1);
        const float w0 = __expf(s0 - sm), w1 = __expf(s1 - sm);
        const float inv = 1.0f / (w0 + w1);
        a0[i] = w0 * inv; a1[i] = w1 * inv;
    }
    for (int o = ob; o < OD; o += 32) {
        const size_t base = ((size_t)b * OD + o) * NHW + nc;
        const f16x8 u = *(const f16x8*)(Op0 + base);
        const f16x8 v = *(const f16x8*)(Op1 + base);
        float4 r0, r1;
        r0.x = a0[0] * (float)u[0] + a1[0] * (float)v[0];
        r0.y = a0[1] * (float)u[1] + a1[1] * (float)v[1];
        r0.z = a0[2] * (float)u[2] + a1[2] * (float)v[2];
        r0.w = a0[3] * (float)u[3] + a1[3] * (float)v[3];
        r1.x = a0[4] * (float)u[4] + a1[4] * (float)v[4];
        r1.y = a0[5] * (float)u[5] + a1[5] * (float)v[5];
        r1.z = a0[6] * (float)u[6] + a1[6] * (float)v[6];
        r1.w = a0[7] * (float)u[7] + a1[7] * (float)v[7];
        *(float4*)&outp[base]     = r0;
        *(float4*)&outp[base + 4] = r1;
    }
}

extern "C" void kernel_launch(void* const* d_in, const int* in_sizes, int n_in,
                              void* d_out, int out_size, void* d_ws, size_t ws_size,
                              hipStream_t stream) {
    const float* xq   = (const float*)d_in[0];
    const float* xs   = (const float*)d_in[1];
    const float* emb  = (const float*)d_in[2];
    const float* mask = (const float*)d_in[3];
    const float* thw  = (const float*)d_in[4];
    const float* thb  = (const float*)d_in[5];
    const float* phw  = (const float*)d_in[6];
    const float* phb  = (const float*)d_in[7];
    float* out = (float*)d_out;

    const size_t szT = (size_t)BN * NHW * OD;   // elements per f16 tensor
    _Float16* Qws = (_Float16*)d_ws;
    _Float16* Op0 = Qws + szT;
    _Float16* Kc  = Op0 + szT;
    _Float16* Vc  = Kc + szT;
    _Float16* wf  = Vc + szT;                   // 2*256*512 f16
    int* idxArr   = (int*)(wf + 2 * OD * CIN);
    int* nbArr    = idxArr + (size_t)BN * NHW;
    int* posArr   = nbArr + 16;
    _Float16* Op1 = (_Float16*)(posArr + (size_t)BN * NHW);
    float* Sarr   = (float*)(Op1 + szT);        // [2][BN][NHW]

    setup<<<dim3(136), 256, 0, stream>>>(thw, phw, wf, mask, idxArr, posArr, nbArr);
    prep_gather<<<dim3(64, 24), 256, 0, stream>>>(xq, xs, wf, thb, phb, posArr,
                                                  emb, idxArr, nbArr, Qws, Kc, Vc);
    flash_attn<<<dim3(256), 512, 0, stream>>>(Qws, Kc, Vc, nbArr, Op0, Op1, Sarr);
    combine<<<dim3(64, BN), 256, 0, stream>>>(Op0, Op1, Sarr, out);
}

// Round 20
// 172.209 us; speedup vs baseline: 1.5504x; 1.0778x over previous
//
#include <hip/hip_runtime.h>
#include <hip/hip_fp16.h>
#include <stdint.h>

typedef _Float16 f16x8 __attribute__((ext_vector_type(8)));
typedef _Float16 f16x4 __attribute__((ext_vector_type(4)));
typedef float    f32x4 __attribute__((ext_vector_type(4)));

#define MFMA16(a, b, c) __builtin_amdgcn_mfma_f32_16x16x32_f16(a, b, c, 0, 0, 0)

static constexpr int BN   = 8;
static constexpr int CIN  = 512;
static constexpr int NHW  = 4096;
static constexpr int OD   = 256;
static constexpr int KBLK = 32;    // PROVEN best tile (r12/r16: ~116us; KBLK=64 regressed)

// 128B-row XOR swizzle (prep LDS tiles)
#define RSWZ(row, cb) ((((row) << 7)) + ((cb) ^ (((row) & 7) << 4)))

__device__ __forceinline__ f16x8 cvt8(const float4 a, const float4 b) {
    f16x8 r;
    r[0] = (_Float16)a.x; r[1] = (_Float16)a.y; r[2] = (_Float16)a.z; r[3] = (_Float16)a.w;
    r[4] = (_Float16)b.x; r[5] = (_Float16)b.y; r[6] = (_Float16)b.z; r[7] = (_Float16)b.w;
    return r;
}

__device__ __forceinline__ uint32_t pkh2(float x, float y) {
    union { _Float16 h[2]; uint32_t u; } z;
    z.h[0] = (_Float16)x; z.h[1] = (_Float16)y;
    return z.u;
}

// ---------------------------------------------------------------------------
// Setup (fused wcvt + compact_mask, block-role dispatch):
//  bid <  128: convert theta/phi weights to f16 (wf[sel][o][c]).
//  bid >= 128: per-batch ordered mask compaction (idx/pos/nbArr).
// ---------------------------------------------------------------------------
__global__ __launch_bounds__(256)
void setup(const float* __restrict__ thw, const float* __restrict__ phw,
           _Float16* __restrict__ wf,
           const float* __restrict__ mask, int* __restrict__ idx,
           int* __restrict__ pos, int* __restrict__ nbArr)
{
    __shared__ int cnt[256];
    __shared__ int pre[257];
    const int t = threadIdx.x;

    if (blockIdx.x < 128) {
        const int i = blockIdx.x * 256 + t;       // 32768 float4 units
        const float4 a = ((const float4*)thw)[i];
        const float4 b = ((const float4*)phw)[i];
        f16x4 ra, rb;
        ra[0] = (_Float16)a.x; ra[1] = (_Float16)a.y; ra[2] = (_Float16)a.z; ra[3] = (_Float16)a.w;
        rb[0] = (_Float16)b.x; rb[1] = (_Float16)b.y; rb[2] = (_Float16)b.z; rb[3] = (_Float16)b.w;
        *(f16x4*)(wf + (size_t)i * 4)          = ra;
        *(f16x4*)(wf + 131072 + (size_t)i * 4) = rb;
        return;
    }

    const int b = blockIdx.x - 128;
    const float* mb = mask + (size_t)b * NHW;
    const int base = t * 16;
    float mv[16];
    int c = 0;
    #pragma unroll
    for (int i = 0; i < 16; ++i) { mv[i] = mb[base + i]; c += (mv[i] != 0.0f); }
    cnt[t] = c;
    __syncthreads();
    if (t == 0) {
        int s = 0;
        for (int i = 0; i < 256; ++i) { pre[i] = s; s += cnt[i]; }
        pre[256] = s;
    }
    __syncthreads();
    int o = pre[t];
    #pragma unroll
    for (int i = 0; i < 16; ++i) {
        if (mv[i] != 0.0f) {
            idx[(size_t)b * NHW + o] = base + i;
            pos[(size_t)b * NHW + base + i] = o;
            ++o;
        } else {
            pos[(size_t)b * NHW + base + i] = -1;
        }
    }
    const int Nb = pre[256];
    const int Npad = (Nb + 63) & ~63;
    for (int k = Nb + t; k < Npad; k += 256) idx[(size_t)b * NHW + k] = 0;
    if (t == 0) { nbArr[b * 2] = Nb; nbArr[b * 2 + 1] = Npad >> 5; }
}

// ---------------------------------------------------------------------------
// Fused prep + gather_v (block-role dispatch on z):
//  z < 16 : prep GEMM. sel=0 (theta) -> linear Qws; sel=1 (phi) -> DIRECT
//           compacted+swizzled Kc at row pos[n] (skip masked rows).
//  z >= 16: gather V columns (b = z-16) into compacted, pre-swizzled Vc.
// grid (64, 24), block 256.
// ---------------------------------------------------------------------------
__global__ __launch_bounds__(256)
void prep_gather(const float* __restrict__ xq, const float* __restrict__ xs,
                 const _Float16* __restrict__ wf,
                 const float* __restrict__ thb, const float* __restrict__ phb,
                 const int* __restrict__ pos,
                 const float* __restrict__ emb, const int* __restrict__ idx,
                 const int* __restrict__ nbArr,
                 _Float16* __restrict__ Qws, _Float16* __restrict__ Kc,
                 _Float16* __restrict__ Vc)
{
    __shared__ __align__(16) char Xs[64 * 128];    // [n][c-chunk 64] f16, swizzled
    __shared__ __align__(16) char Ws[256 * 128];   // [o][c-chunk 64] f16, swizzled
    __shared__ int Ps[64];
    __shared__ int sidx[64];

    const int t    = threadIdx.x;
    const int z    = blockIdx.y;

    if (z >= 16) {
        // ---- gather_v role ----
        const int b = z - 16, k0 = blockIdx.x * 64;
        const int Nb = nbArr[b * 2];
        const int Npad = (Nb + 63) & ~63;
        if (k0 >= Npad) return;
        if (t < 64) sidx[t] = idx[(size_t)b * NHW + k0 + t];
        __syncthreads();
        const float* eb = emb + (size_t)b * OD * NHW;
        char* VcB = (char*)(Vc + (size_t)b * OD * NHW);
        #pragma unroll
        for (int r = 0; r < 8; ++r) {
            const int u = r * 256 + t;             // 256 o x 8 units
            const int o = u >> 3, uc = u & 7;
            const int chunk = uc >> 2, uin = uc & 3;
            float4 a, c;
            #pragma unroll
            for (int i = 0; i < 4; ++i) ((float*)&a)[i] = eb[(size_t)o * NHW + sidx[uc * 8 + i]];
            #pragma unroll
            for (int i = 0; i < 4; ++i) ((float*)&c)[i] = eb[(size_t)o * NHW + sidx[uc * 8 + 4 + i]];
            const f16x8 v = cvt8(a, c);
            *(f16x8*)(VcB + (size_t)o * (NHW * 2) + (size_t)k0 * 2 + chunk * 64
                          + ((uin ^ ((o >> 1) & 3)) * 16)) = v;
        }
        return;
    }

    // ---- prep GEMM role ----
    const int nt = blockIdx.x;
    const int b = z >> 1, sel = z & 1;
    const float* x        = (sel ? xs : xq) + (size_t)b * CIN * NHW;
    const _Float16* w     = wf + (size_t)sel * (OD * CIN);
    const float* bias     = sel ? phb : thb;
    const int n0 = nt * 64;

    const int lane = t & 63, wave = t >> 6;
    const int l16  = lane & 15, lh = lane >> 4;

    if (sel && t < 64) Ps[t] = pos[(size_t)b * NHW + n0 + t];

    f32x4 acc[4][4] = {};   // [oo][nn]: rows o = wave*64+oo*16+4lh+r, cols n = nn*16+l16

    for (int c0 = 0; c0 < CIN; c0 += 64) {
        #pragma unroll
        for (int rep = 0; rep < 4; ++rep) {
            const int ci = rep * 16 + (t >> 4);
            const int nl = (t & 15) * 4;
            const float4 v = *(const float4*)&x[(size_t)(c0 + ci) * NHW + n0 + nl];
            *(_Float16*)(Xs + RSWZ(nl + 0, ci * 2)) = (_Float16)v.x;
            *(_Float16*)(Xs + RSWZ(nl + 1, ci * 2)) = (_Float16)v.y;
            *(_Float16*)(Xs + RSWZ(nl + 2, ci * 2)) = (_Float16)v.z;
            *(_Float16*)(Xs + RSWZ(nl + 3, ci * 2)) = (_Float16)v.w;
        }
        #pragma unroll
        for (int r = 0; r < 8; ++r) {
            const int u = r * 256 + t;
            const int o = u >> 3, cs8 = (u & 7) * 8;
            const f16x8 v = *(const f16x8*)(w + (size_t)o * CIN + c0 + cs8);
            *(f16x8*)(Ws + RSWZ(o, cs8 * 2)) = v;
        }
        __syncthreads();

        #pragma unroll
        for (int kk = 0; kk < 2; ++kk) {
            f16x8 af[4];
            #pragma unroll
            for (int oo = 0; oo < 4; ++oo)
                af[oo] = *(const f16x8*)(Ws + RSWZ(wave * 64 + oo * 16 + l16, kk * 64 + lh * 16));
            #pragma unroll
            for (int nn = 0; nn < 4; ++nn) {
                const f16x8 bf = *(const f16x8*)(Xs + RSWZ(nn * 16 + l16, kk * 64 + lh * 16));
                #pragma unroll
                for (int oo = 0; oo < 4; ++oo)
                    acc[oo][nn] = MFMA16(af[oo], bf, acc[oo][nn]);
            }
        }
        __syncthreads();
    }

    if (!sel) {
        _Float16* out = Qws + (size_t)b * NHW * OD;
        #pragma unroll
        for (int oo = 0; oo < 4; ++oo) {
            const float4 bi = *(const float4*)&bias[wave * 64 + oo * 16 + lh * 4];
            #pragma unroll
            for (int nn = 0; nn < 4; ++nn) {
                f16x4 v;
                v[0] = (_Float16)(acc[oo][nn][0] + bi.x);
                v[1] = (_Float16)(acc[oo][nn][1] + bi.y);
                v[2] = (_Float16)(acc[oo][nn][2] + bi.z);
                v[3] = (_Float16)(acc[oo][nn][3] + bi.w);
                const int n = n0 + nn * 16 + l16;
                *(f16x4*)&out[(size_t)n * OD + wave * 64 + oo * 16 + lh * 4] = v;
            }
        }
    } else {
        char* KcB = (char*)(Kc + (size_t)b * NHW * OD);
        #pragma unroll
        for (int oo = 0; oo < 4; ++oo) {
            const float4 bi = *(const float4*)&bias[wave * 64 + oo * 16 + lh * 4];
            const int o = wave * 64 + oo * 16 + lh * 4;
            #pragma unroll
            for (int nn = 0; nn < 4; ++nn) {
                const int k = Ps[nn * 16 + l16];
                if (k >= 0) {
                    f16x4 v;
                    v[0] = (_Float16)(acc[oo][nn][0] + bi.x);
                    v[1] = (_Float16)(acc[oo][nn][1] + bi.y);
                    v[2] = (_Float16)(acc[oo][nn][2] + bi.z);
                    v[3] = (_Float16)(acc[oo][nn][3] + bi.w);
                    *(f16x4*)(KcB + (size_t)k * 512
                              + (((o >> 3) * 16) ^ ((k & 7) << 4))
                              + ((o >> 2) & 1) * 8) = v;
                }
            }
        }
    }
}

// ---------------------------------------------------------------------------
// Flash attention — r12/16 inner loop + T5 setprio, now with TRIPLE-BUFFERED
// DMA staging and COUNTED vmcnt (T4): the barrier no longer drains the
// in-flight next-tile DMA (old __syncthreads forced vmcnt(0) each iter).
// Steady state: wait vmcnt(4) [= keep newest stage's 4 loads in flight],
// raw s_barrier, issue stage(i+2), compute tile i. Each tile's DMA gets ~2
// iterations of flight. Buffer safety: stage(i+2) overwrites buf[(i-1)%3],
// whose reader compute(i-1) completed before this iteration's barrier.
// grid 256: b=bid&7, u=bid>>3, qt=u>>1, half=u&1. LDS 96 KB, 1 block/CU.
// ---------------------------------------------------------------------------
__device__ __forceinline__ void stage_dma(const char* __restrict__ Kb,
                                          const char* __restrict__ Vb,
                                          int j, int t, int wbase,
                                          char* Kld, char* Vld)
{
    typedef __attribute__((address_space(1))) const unsigned int gu32;
    typedef __attribute__((address_space(3))) unsigned int lu32;
    const char* kb = Kb + (size_t)j * (KBLK * 512);
    #pragma unroll
    for (int r = 0; r < 2; ++r) {
        __builtin_amdgcn_global_load_lds(
            (gu32*)(kb + (size_t)(r * 512 + t) * 16),
            (lu32*)(Kld + (r * 512 + wbase) * 16), 16, 0, 0);
    }
    #pragma unroll
    for (int r = 0; r < 2; ++r) {
        const int u = r * 512 + t, o = u >> 2, sl = u & 3;
        __builtin_amdgcn_global_load_lds(
            (gu32*)(Vb + (size_t)o * (NHW * 2) + (size_t)j * 64 + sl * 16),
            (lu32*)(Vld + (r * 512 + wbase) * 16), 16, 0, 0);
    }
}

__global__ __launch_bounds__(512, 1)
void flash_attn(const _Float16* __restrict__ Qws, const _Float16* __restrict__ Kc,
                const _Float16* __restrict__ Vc, const int* __restrict__ nbArr,
                _Float16* __restrict__ Op0, _Float16* __restrict__ Op1,
                float* __restrict__ Sarr)
{
    const int bid = blockIdx.x;
    const int b = bid & 7, u = bid >> 3;
    const int qt = u >> 1, half = u & 1;
    const int t = threadIdx.x, lane = t & 63, wave = t >> 6;
    const int l16 = lane & 15, lh = lane >> 4;
    const int wbase = wave << 6;

    __shared__ __align__(16) char Kl[3][KBLK * 512];   // 3 x 16 KB (swizzled)
    __shared__ __align__(16) char Vl[3][OD * 64];      // 3 x 16 KB (swizzled)

    const _Float16* Qb = Qws + (size_t)b * NHW * OD;
    const char* Kb = (const char*)(Kc + (size_t)b * NHW * OD);
    const char* Vb = (const char*)(Vc + (size_t)b * OD * NHW);
    const int Nb = nbArr[b * 2];
    const int nt = nbArr[b * 2 + 1];
    const int nth = (nt + 1) >> 1;
    const int j0 = half ? nth : 0;
    const int j1 = half ? nt : nth;
    const int nl = j1 - j0;

    // Q fragments, 2 groups: lane l16 = q-row within group
    f16x8 qf[8][2];
    #pragma unroll
    for (int g = 0; g < 2; ++g) {
        const _Float16* qrow = Qb
            + (size_t)(qt * 256 + wave * 32 + g * 16 + l16) * OD + lh * 8;
        #pragma unroll
        for (int kk = 0; kk < 8; ++kk) qf[kk][g] = *(const f16x8*)(qrow + kk * 32);
    }

    f32x4 accO[16][2] = {};          // D[o][q] per group
    float M0 = -INFINITY, L0 = 0.f;
    float M1 = -INFINITY, L1 = 0.f;

    // prologue: stage tiles j0, j0+1 into buffers 0,1 (in issue order)
    if (nl > 0) stage_dma(Kb, Vb, j0, t, wbase, Kl[0], Vl[0]);
    if (nl > 1) stage_dma(Kb, Vb, j0 + 1, t, wbase, Kl[1], Vl[1]);

    #pragma unroll 1
    for (int i = 0; i < nl; ++i) {
        // ---- counted wait: DMA(i) complete (in-order retirement), DMA(i+1)
        //      (the newest 4 loads) may stay in flight across the barrier.
        if (i + 1 < nl) { asm volatile("s_waitcnt vmcnt(4)" ::: "memory"); }
        else            { asm volatile("s_waitcnt vmcnt(0)" ::: "memory"); }
        __builtin_amdgcn_s_barrier();

        const int jt = j0 + i;
        const int cur = i % 3;
        // ---- issue DMA for tile i+2 (overwrites buf[(i-1)%3], safe: its
        //      reader compute(i-1) finished before the barrier above)
        if (i + 2 < nl) stage_dma(Kb, Vb, jt + 2, t, wbase,
                                  Kl[(i + 2) % 3], Vl[(i + 2) % 3]);

        // ---- S' = K Q^T (swapped): each kf read feeds BOTH q-groups
        f32x4 S[2][2] = {};
        __builtin_amdgcn_s_setprio(1);
        #pragma unroll
        for (int ct = 0; ct < 2; ++ct) {
            const int row = ct * 16 + l16;
            #pragma unroll
            for (int kk = 0; kk < 8; ++kk) {
                const f16x8 kf = *(const f16x8*)(Kl[cur] + row * 512
                                     + ((kk * 64 + lh * 16) ^ ((row & 7) << 4)));
                S[ct][0] = MFMA16(kf, qf[kk][0], S[ct][0]);
                S[ct][1] = MFMA16(kf, qf[kk][1], S[ct][1]);
            }
        }
        __builtin_amdgcn_s_setprio(0);

        // ---- logits
        const bool tail = (jt * 32 + 32 > Nb);
        float lg[8][2];
        #pragma unroll
        for (int ct = 0; ct < 2; ++ct)
            #pragma unroll
            for (int r = 0; r < 4; ++r) {
                float v0 = S[ct][0][r] * 0.25f;
                float v1 = S[ct][1][r] * 0.25f;
                if (tail) {
                    const int kg = jt * 32 + ct * 16 + lh * 4 + r;
                    if (kg >= Nb) { v0 = -1e30f; v1 = -1e30f; }
                }
                lg[ct * 4 + r][0] = v0;
                lg[ct * 4 + r][1] = v1;
            }

        // ---- per-lane row max (per group)
        float m80 = lg[0][0], m81 = lg[0][1];
        #pragma unroll
        for (int i2 = 1; i2 < 8; ++i2) { m80 = fmaxf(m80, lg[i2][0]); m81 = fmaxf(m81, lg[i2][1]); }
        m80 = fmaxf(m80, __shfl_xor(m80, 16));
        m80 = fmaxf(m80, __shfl_xor(m80, 32));
        m81 = fmaxf(m81, __shfl_xor(m81, 16));
        m81 = fmaxf(m81, __shfl_xor(m81, 32));

        // ---- deferred rescale (THR=8)
        if (__any((m80 > M0 + 8.0f) || (m81 > M1 + 8.0f))) {
            const float nm0 = fmaxf(M0, m80), nm1 = fmaxf(M1, m81);
            const float f0 = __expf(M0 - nm0), f1 = __expf(M1 - nm1);
            M0 = nm0; L0 *= f0; M1 = nm1; L1 *= f1;
            #pragma unroll
            for (int oo = 0; oo < 16; ++oo)
                #pragma unroll
                for (int r = 0; r < 4; ++r) {
                    accO[oo][0][r] *= f0;
                    accO[oo][1][r] *= f1;
                }
        }

        // ---- P = exp(lg - M), row sums (per group), in-place over lg
        float s0 = 0.f, s1 = 0.f;
        #pragma unroll
        for (int i2 = 0; i2 < 8; ++i2) {
            lg[i2][0] = __expf(lg[i2][0] - M0); s0 += lg[i2][0];
            lg[i2][1] = __expf(lg[i2][1] - M1); s1 += lg[i2][1];
        }
        s0 += __shfl_xor(s0, 16); s0 += __shfl_xor(s0, 32); L0 += s0;
        s1 += __shfl_xor(s1, 16); s1 += __shfl_xor(s1, 32); L1 += s1;

        // ---- re-fragment P per group (pull both halves, select by dest lh&2)
        const int src0 = l16 + (((2 * lh) & 3) << 4);
        const int src1 = src0 + 16;
        const bool hi = (lh & 2) != 0;
        f16x8 pf[2];
        #pragma unroll
        for (int g = 0; g < 2; ++g) {
            const uint32_t ps0 = pkh2(lg[0][g], lg[1][g]), ps1 = pkh2(lg[2][g], lg[3][g]);
            const uint32_t ps2 = pkh2(lg[4][g], lg[5][g]), ps3 = pkh2(lg[6][g], lg[7][g]);
            const uint32_t a0 = __shfl(ps0, src0), a2 = __shfl(ps2, src0);
            const uint32_t a1 = __shfl(ps1, src0), a3 = __shfl(ps3, src0);
            const uint32_t b0 = __shfl(ps0, src1), b2 = __shfl(ps2, src1);
            const uint32_t b1 = __shfl(ps1, src1), b3 = __shfl(ps3, src1);
            union { uint32_t u[4]; f16x8 v; } pu;
            pu.u[0] = hi ? a2 : a0;
            pu.u[1] = hi ? a3 : a1;
            pu.u[2] = hi ? b2 : b0;
            pu.u[3] = hi ? b3 : b1;
            pf[g] = pu.v;
        }

        // ---- O += V^T P : each vf read feeds BOTH q-groups
        __builtin_amdgcn_s_setprio(1);
        #pragma unroll
        for (int oo = 0; oo < 16; ++oo) {
            const int o = oo * 16 + l16;
            const f16x8 vf = *(const f16x8*)(Vl[cur] + o * 64
                                 + ((lh * 16) ^ (((o >> 1) & 3) << 4)));
            accO[oo][0] = MFMA16(vf, pf[0], accO[oo][0]);
            accO[oo][1] = MFMA16(vf, pf[1], accO[oo][1]);
        }
        __builtin_amdgcn_s_setprio(0);
    }

    // ---- epilogue: normalized partial (f16) + S = M + ln L (f32)
    _Float16* Od = half ? Op1 : Op0;
    float*    Sd = Sarr + (size_t)half * (BN * NHW) + (size_t)b * NHW;
    const float rl0 = 1.0f / fmaxf(L0, 1e-30f);
    const float rl1 = 1.0f / fmaxf(L1, 1e-30f);
    const int n0 = qt * 256 + wave * 32 + l16;
    if (lh == 0) {
        Sd[n0]      = (L0 > 0.f) ? (M0 + __logf(L0)) : -1e30f;
        Sd[n0 + 16] = (L1 > 0.f) ? (M1 + __logf(L1)) : -1e30f;
    }
    #pragma unroll
    for (int oo = 0; oo < 16; ++oo) {
        #pragma unroll
        for (int r = 0; r < 4; ++r) {
            const int o = oo * 16 + lh * 4 + r;
            _Float16* row = Od + ((size_t)b * OD + o) * NHW;
            row[n0]      = (_Float16)(accO[oo][0][r] * rl0);
            row[n0 + 16] = (_Float16)(accO[oo][1][r] * rl1);
        }
    }
}

// ---------------------------------------------------------------------------
// Combine: out = (w0*O0 + w1*O1)/(w0+w1), w_h = exp(S_h - max(S0,S1)).
// grid (64 n-tiles, 8 b), block 256. Thread: 8-n chunk x 8 o-rows.
// ---------------------------------------------------------------------------
__global__ __launch_bounds__(256)
void combine(const _Float16* __restrict__ Op0, const _Float16* __restrict__ Op1,
             const float* __restrict__ Sarr, float* __restrict__ outp)
{
    const int b = blockIdx.y;
    const int n0 = blockIdx.x * 64;
    const int t = threadIdx.x;
    const int nc = n0 + (t & 7) * 8;
    const int ob = t >> 3;          // 0..31
    const float* S0 = Sarr + (size_t)b * NHW;
    const float* S1 = Sarr + (size_t)BN * NHW + (size_t)b * NHW;

    float a0[8], a1[8];
    #pragma unroll
    for (int i = 0; i < 8; ++i) {
        const float s0 = S0[nc + i], s1 = S1[nc + i];
        const float sm = fmaxf(s0, s1);
        const float w0 = __expf(s0 - sm), w1 = __expf(s1 - sm);
        const float inv = 1.0f / (w0 + w1);
        a0[i] = w0 * inv; a1[i] = w1 * inv;
    }
    for (int o = ob; o < OD; o += 32) {
        const size_t base = ((size_t)b * OD + o) * NHW + nc;
        const f16x8 u = *(const f16x8*)(Op0 + base);
        const f16x8 v = *(const f16x8*)(Op1 + base);
        float4 r0, r1;
        r0.x = a0[0] * (float)u[0] + a1[0] * (float)v[0];
        r0.y = a0[1] * (float)u[1] + a1[1] * (float)v[1];
        r0.z = a0[2] * (float)u[2] + a1[2] * (float)v[2];
        r0.w = a0[3] * (float)u[3] + a1[3] * (float)v[3];
        r1.x = a0[4] * (float)u[4] + a1[4] * (float)v[4];
        r1.y = a0[5] * (float)u[5] + a1[5] * (float)v[5];
        r1.z = a0[6] * (float)u[6] + a1[6] * (float)v[6];
        r1.w = a0[7] * (float)u[7] + a1[7] * (float)v[7];
        *(float4*)&outp[base]     = r0;
        *(float4*)&outp[base + 4] = r1;
    }
}

extern "C" void kernel_launch(void* const* d_in, const int* in_sizes, int n_in,
                              void* d_out, int out_size, void* d_ws, size_t ws_size,
                              hipStream_t stream) {
    const float* xq   = (const float*)d_in[0];
    const float* xs   = (const float*)d_in[1];
    const float* emb  = (const float*)d_in[2];
    const float* mask = (const float*)d_in[3];
    const float* thw  = (const float*)d_in[4];
    const float* thb  = (const float*)d_in[5];
    const float* phw  = (const float*)d_in[6];
    const float* phb  = (const float*)d_in[7];
    float* out = (float*)d_out;

    const size_t szT = (size_t)BN * NHW * OD;   // elements per f16 tensor
    _Float16* Qws = (_Float16*)d_ws;
    _Float16* Op0 = Qws + szT;
    _Float16* Kc  = Op0 + szT;
    _Float16* Vc  = Kc + szT;
    _Float16* wf  = Vc + szT;                   // 2*256*512 f16
    int* idxArr   = (int*)(wf + 2 * OD * CIN);
    int* nbArr    = idxArr + (size_t)BN * NHW;
    int* posArr   = nbArr + 16;
    _Float16* Op1 = (_Float16*)(posArr + (size_t)BN * NHW);
    float* Sarr   = (float*)(Op1 + szT);        // [2][BN][NHW]

    setup<<<dim3(136), 256, 0, stream>>>(thw, phw, wf, mask, idxArr, posArr, nbArr);
    prep_gather<<<dim3(64, 24), 256, 0, stream>>>(xq, xs, wf, thb, phb, posArr,
                                                  emb, idxArr, nbArr, Qws, Kc, Vc);
    flash_attn<<<dim3(256), 512, 0, stream>>>(Qws, Kc, Vc, nbArr, Op0, Op1, Sarr);
    combine<<<dim3(64, BN), 256, 0, stream>>>(Op0, Op1, Sarr, out);
}